// Round 3
// baseline (305.532 us; speedup 1.0000x reference)
//
#include <hip/hip_runtime.h>
#include <hip/hip_bf16.h>

// ---------- helpers ----------
__device__ __forceinline__ unsigned short f2bf(float f) {
    unsigned u = __float_as_uint(f);
    unsigned r = (u + 0x7fffu + ((u >> 16) & 1u)) >> 16;   // RNE
    return (unsigned short)r;
}
__device__ __forceinline__ float bfu(unsigned short s) {
    return __uint_as_float(((unsigned)s) << 16);
}
__device__ __forceinline__ float blo(unsigned u) { return __uint_as_float(u << 16); }
__device__ __forceinline__ float bhi(unsigned u) { return __uint_as_float(u & 0xffff0000u); }

__device__ __forceinline__ float dot8_relu(const uint4 a, const uint4 b, const float* w2r) {
    float acc;
    acc  = w2r[0] * fmaxf(blo(a.x) + blo(b.x), 0.f);
    acc += w2r[1] * fmaxf(bhi(a.x) + bhi(b.x), 0.f);
    acc += w2r[2] * fmaxf(blo(a.y) + blo(b.y), 0.f);
    acc += w2r[3] * fmaxf(bhi(a.y) + bhi(b.y), 0.f);
    acc += w2r[4] * fmaxf(blo(a.z) + blo(b.z), 0.f);
    acc += w2r[5] * fmaxf(bhi(a.z) + bhi(b.z), 0.f);
    acc += w2r[6] * fmaxf(blo(a.w) + blo(b.w), 0.f);
    acc += w2r[7] * fmaxf(bhi(a.w) + bhi(b.w), 0.f);
    return acc;
}

// ---------- kernel 1: init ----------
__global__ void init_kernel(float* __restrict__ denom, float* __restrict__ ynum, int N) {
    int i = blockIdx.x * 256 + threadIdx.x;
    if (i < N) { denom[i] = 0.f; ynum[i] = 0.f; }
}

// ---------- kernel 2: node projection ----------
__global__ __launch_bounds__(256) void proj_kernel(
    const float* __restrict__ x, const float* __restrict__ w1, const float* __restrict__ b1,
    unsigned short* __restrict__ P, int N)
{
    __shared__ unsigned short wl[64 * 256];  // 32 KB
    __shared__ float xs[32 * 64];            // 8 KB
    const int t = threadIdx.x;

    for (int i = t; i < 64 * 256; i += 256) {
        int k = i >> 8, j = i & 255;
        float w = (j < 128) ? w1[k * 128 + j] : w1[(64 + k) * 128 + (j - 128)];
        wl[i] = f2bf(w);
    }
    const int n0 = blockIdx.x * 32;
    for (int i = t; i < 32 * 64; i += 256) {
        int n = n0 + (i >> 6);
        xs[i] = (n < N) ? x[(size_t)n * 64 + (i & 63)] : 0.f;
    }
    __syncthreads();

    const int jg = t & 63;
    const int ng = t >> 6;
    const int j0 = jg * 4;

    float acc[8][4];
#pragma unroll
    for (int i = 0; i < 8; ++i)
#pragma unroll
        for (int c = 0; c < 4; ++c) acc[i][c] = 0.f;

    for (int k = 0; k < 64; k += 4) {
        float wv[4][4];
#pragma unroll
        for (int kk = 0; kk < 4; ++kk) {
            ushort4 wu = *(const ushort4*)&wl[(k + kk) * 256 + j0];
            wv[kk][0] = bfu(wu.x); wv[kk][1] = bfu(wu.y);
            wv[kk][2] = bfu(wu.z); wv[kk][3] = bfu(wu.w);
        }
#pragma unroll
        for (int i = 0; i < 8; ++i) {
            const float4 xv = *(const float4*)&xs[(ng * 8 + i) * 64 + k];
#pragma unroll
            for (int c = 0; c < 4; ++c)
                acc[i][c] += xv.x * wv[0][c] + xv.y * wv[1][c] + xv.z * wv[2][c] + xv.w * wv[3][c];
        }
    }

    float bb[4] = {0.f, 0.f, 0.f, 0.f};
    if (j0 < 128) {
#pragma unroll
        for (int c = 0; c < 4; ++c) bb[c] = b1[j0 + c];
    }

#pragma unroll
    for (int i = 0; i < 8; ++i) {
        int n = n0 + ng * 8 + i;
        if (n < N) {
            ushort4 st;
            st.x = f2bf(acc[i][0] + bb[0]);
            st.y = f2bf(acc[i][1] + bb[1]);
            st.z = f2bf(acc[i][2] + bb[2]);
            st.w = f2bf(acc[i][3] + bb[3]);
            *(ushort4*)(P + (size_t)n * 256 + j0) = st;
        }
    }
}

// ---------- kernel 3: fused edge logit -> exp -> scatter (denom, ynum) ----------
// 16 lanes per edge, 2 edges per slot iteration (MLP). After the butterfly
// reduction every lane holds both logits; atomics are spread across lanes
// 0/4/8/12 so no lane issues two atomics and denom/ynum are separate arrays.
__global__ __launch_bounds__(256) void edge_main_kernel(
    const unsigned short* __restrict__ P, const int* __restrict__ ei,
    const float* __restrict__ y,
    const float* __restrict__ w2, const float* __restrict__ b2,
    float* __restrict__ elog, float* __restrict__ denom, float* __restrict__ ynum, int E)
{
    const int lane = threadIdx.x & 15;
    float w2r[8];
#pragma unroll
    for (int c = 0; c < 8; ++c) w2r[c] = w2[lane * 8 + c];
    const float b2s = b2[0];

    const int slot = (blockIdx.x * 256 + threadIdx.x) >> 4;
    const int nslots = (gridDim.x * 256) >> 4;

    for (int e0 = slot * 2; e0 < E; e0 += nslots * 2) {
        const int e1 = e0 + 1;
        const bool has1 = (e1 < E);

        const int s0 = ei[e0];
        const int d0 = ei[E + e0];
        const int s1 = has1 ? ei[e1] : s0;
        const int d1 = has1 ? ei[E + e1] : d0;

        // issue all four gathers before any compute
        const uint4 a0 = *(const uint4*)(P + (size_t)s0 * 256 + lane * 8);
        const uint4 b0 = *(const uint4*)(P + (size_t)d0 * 256 + 128 + lane * 8);
        const uint4 a1 = *(const uint4*)(P + (size_t)s1 * 256 + lane * 8);
        const uint4 b1 = *(const uint4*)(P + (size_t)d1 * 256 + 128 + lane * 8);

        float acc0 = dot8_relu(a0, b0, w2r);
        float acc1 = dot8_relu(a1, b1, w2r);

        acc0 += __shfl_xor(acc0, 1);  acc1 += __shfl_xor(acc1, 1);
        acc0 += __shfl_xor(acc0, 2);  acc1 += __shfl_xor(acc1, 2);
        acc0 += __shfl_xor(acc0, 4);  acc1 += __shfl_xor(acc1, 4);
        acc0 += __shfl_xor(acc0, 8);  acc1 += __shfl_xor(acc1, 8);

        if (lane == 0) {
            float ev = __expf(acc0 + b2s);
            elog[e0] = ev;
            atomicAdd(&denom[d0], ev);
        } else if (lane == 4) {
            float ev = __expf(acc0 + b2s);
            atomicAdd(&ynum[d0], y[s0] * ev);
        } else if (lane == 8 && has1) {
            float ev = __expf(acc1 + b2s);
            elog[e1] = ev;
            atomicAdd(&denom[d1], ev);
        } else if (lane == 12 && has1) {
            float ev = __expf(acc1 + b2s);
            atomicAdd(&ynum[d1], y[s1] * ev);
        }
    }
}

// ---------- kernel 4: y_hat = ynum/denom, inv_denom = 1/denom ----------
__global__ void node_final_kernel(const float* __restrict__ denom,
                                  const float* __restrict__ ynum,
                                  float* __restrict__ inv_denom,
                                  float* __restrict__ yhat, int N) {
    int i = blockIdx.x * 256 + threadIdx.x;
    if (i >= N) return;
    float dnm = denom[i];
    if (dnm != 0.f) {
        yhat[i] = ynum[i] / dnm;
        inv_denom[i] = 1.0f / dnm;
    } else {
        yhat[i] = 0.f;
        inv_denom[i] = 0.f;
    }
}

// ---------- kernel 5: alpha = e * inv_denom[dst]  (no atomics, streaming) ----------
__global__ __launch_bounds__(256) void alpha_norm_kernel(
    const int* __restrict__ ei, float* __restrict__ elog,
    const float* __restrict__ inv_denom, int E)
{
    int e = blockIdx.x * 256 + threadIdx.x;
    if (e >= E) return;
    int d = ei[E + e];
    elog[e] = elog[e] * inv_denom[d];
}

extern "C" void kernel_launch(void* const* d_in, const int* in_sizes, int n_in,
                              void* d_out, int out_size, void* d_ws, size_t ws_size,
                              hipStream_t stream) {
    const float* x  = (const float*)d_in[0];
    const float* y  = (const float*)d_in[1];
    const int*   ei = (const int*)d_in[2];
    const float* w1 = (const float*)d_in[3];
    const float* b1 = (const float*)d_in[4];
    const float* w2 = (const float*)d_in[5];
    const float* b2 = (const float*)d_in[6];

    const int N = in_sizes[1];
    const int E = in_sizes[2] / 2;

    float* out  = (float*)d_out;
    float* yhat = out;          // [N]
    float* elog = out + N;      // [E] — exp values, then alpha in place

    char* ws = (char*)d_ws;
    unsigned short* P = (unsigned short*)ws;                   // N*256 bf16 = 25.6 MB
    size_t Pbytes = (size_t)N * 256 * sizeof(unsigned short);
    float* denom = (float*)(ws + Pbytes);                      // N f32
    float* ynum  = denom + N;                                  // N f32
    float* inv_d = ynum + N;                                   // N f32

    init_kernel<<<(N + 255) / 256, 256, 0, stream>>>(denom, ynum, N);
    proj_kernel<<<(N + 31) / 32, 256, 0, stream>>>(x, w1, b1, P, N);
    edge_main_kernel<<<2048, 256, 0, stream>>>(P, ei, y, w2, b2, elog, denom, ynum, E);
    node_final_kernel<<<(N + 255) / 256, 256, 0, stream>>>(denom, ynum, inv_d, yhat, N);
    alpha_norm_kernel<<<(E + 255) / 256, 256, 0, stream>>>(ei, elog, inv_d, E);
}